// Round 1
// 6724.127 us; speedup vs baseline: 1.2142x; 1.2142x over previous
//
#include <hip/hip_runtime.h>
#include <hip/hip_fp16.h>

#define T_LEN 1024
#define B_SZ  32
#define D_IN  768
#define H_SZ  768
#define G4    3072   // 4*H
#define FPAD  32     // flag padding: 1 flag per 128-byte line
#define LDA   40     // padded LDS row stride (bf16 elems) for 32-wide K tiles

typedef __attribute__((ext_vector_type(8))) short short8;  // 8 bf16 (4 VGPRs)
typedef __attribute__((ext_vector_type(4))) float f32x4;   // MFMA 16x16 C/D frag

// ---------------------------------------------------------------------------
// Phase A: xg[(t*32+b)][g] = hidden[b][t][:] . W_ih[g][:] + b_ih[g] + b_hh[g]
// Split-bf16 3-term MFMA GEMM: a = ah + al (bf16 hi/lo), w = wh + wl.
// acc += ah*wh + ah*wl + al*wh  (al*wl term ~2^-16 rel, dropped).
// Per-term error ~2^-16 relative -> below the existing fp16-xg store noise,
// so end-to-end absmax is unchanged vs the fp32 VALU GEMM.
// 128x128 tile, BK=32, 4 waves (2x2), each wave 64x64 via 4x4 16x16x32 frags.
// ---------------------------------------------------------------------------
__global__ __launch_bounds__(256, 2)
void xg_gemm(const float* __restrict__ hidden, const float* __restrict__ W_ih,
             const float* __restrict__ b_ih, const float* __restrict__ b_hh,
             __half* __restrict__ xg)
{
    __shared__ unsigned short Ah[128 * LDA];
    __shared__ unsigned short Al[128 * LDA];
    __shared__ unsigned short Bh[128 * LDA];
    __shared__ unsigned short Bl[128 * LDA];

    const int tid = threadIdx.x;
    const int n0 = blockIdx.x * 128;
    const int m0 = blockIdx.y * 128;

    // staging role: thread -> (row 0..127, k-half 0/16); 64B (one line) each.
    const int srow = tid >> 1;
    const int skh  = (tid & 1) * 16;
    const int m = m0 + srow;
    const float* arow = hidden + ((size_t)(m & 31) * T_LEN + (m >> 5)) * D_IN;
    const float* brow = W_ih + (size_t)(n0 + srow) * D_IN;

    // compute role
    const int lane = tid & 63;
    const int wid  = tid >> 6;
    const int wm = (wid >> 1) * 64;       // wave row base within tile
    const int wn = (wid & 1) * 64;        // wave col base within tile
    const int fr = lane & 15;             // frag row (A) / col (B,D)
    const int fk = (lane >> 4) * 8;       // frag k offset (8 contiguous bf16)

    f32x4 acc[4][4];
#pragma unroll
    for (int i = 0; i < 4; ++i)
#pragma unroll
        for (int j = 0; j < 4; ++j) acc[i][j] = (f32x4)0.f;

    // prologue: load K-tile 0 into registers (global latency off the barrier)
    float4 av[4], bv[4];
#pragma unroll
    for (int q = 0; q < 4; ++q) {
        av[q] = *(const float4*)(arow + skh + 4 * q);
        bv[q] = *(const float4*)(brow + skh + 4 * q);
    }

    for (int kb = 0; kb < D_IN; kb += 32) {
        __syncthreads();   // previous compute done reading LDS

        // ---- convert fp32 -> bf16 hi/lo (bitwise split, lo exact in fp32) ----
        {
            const float* f = (const float*)av;
            unsigned int hp[8], lp[8];
#pragma unroll
            for (int p = 0; p < 8; ++p) {
                const unsigned int u0 = __float_as_uint(f[2 * p]);
                const unsigned int u1 = __float_as_uint(f[2 * p + 1]);
                const unsigned int h0 = u0 & 0xffff0000u, h1 = u1 & 0xffff0000u;
                hp[p] = (h0 >> 16) | h1;
                const float l0 = f[2 * p]     - __uint_as_float(h0);
                const float l1 = f[2 * p + 1] - __uint_as_float(h1);
                lp[p] = (__float_as_uint(l0) >> 16) | (__float_as_uint(l1) & 0xffff0000u);
            }
            *(uint4*)&Ah[srow * LDA + skh]     = make_uint4(hp[0], hp[1], hp[2], hp[3]);
            *(uint4*)&Ah[srow * LDA + skh + 8] = make_uint4(hp[4], hp[5], hp[6], hp[7]);
            *(uint4*)&Al[srow * LDA + skh]     = make_uint4(lp[0], lp[1], lp[2], lp[3]);
            *(uint4*)&Al[srow * LDA + skh + 8] = make_uint4(lp[4], lp[5], lp[6], lp[7]);
        }
        {
            const float* f = (const float*)bv;
            unsigned int hp[8], lp[8];
#pragma unroll
            for (int p = 0; p < 8; ++p) {
                const unsigned int u0 = __float_as_uint(f[2 * p]);
                const unsigned int u1 = __float_as_uint(f[2 * p + 1]);
                const unsigned int h0 = u0 & 0xffff0000u, h1 = u1 & 0xffff0000u;
                hp[p] = (h0 >> 16) | h1;
                const float l0 = f[2 * p]     - __uint_as_float(h0);
                const float l1 = f[2 * p + 1] - __uint_as_float(h1);
                lp[p] = (__float_as_uint(l0) >> 16) | (__float_as_uint(l1) & 0xffff0000u);
            }
            *(uint4*)&Bh[srow * LDA + skh]     = make_uint4(hp[0], hp[1], hp[2], hp[3]);
            *(uint4*)&Bh[srow * LDA + skh + 8] = make_uint4(hp[4], hp[5], hp[6], hp[7]);
            *(uint4*)&Bl[srow * LDA + skh]     = make_uint4(lp[0], lp[1], lp[2], lp[3]);
            *(uint4*)&Bl[srow * LDA + skh + 8] = make_uint4(lp[4], lp[5], lp[6], lp[7]);
        }
        __syncthreads();

        // issue next K-tile loads; latency hides under the 48 MFMAs
        if (kb + 32 < D_IN) {
#pragma unroll
            for (int q = 0; q < 4; ++q) {
                av[q] = *(const float4*)(arow + kb + 32 + skh + 4 * q);
                bv[q] = *(const float4*)(brow + kb + 32 + skh + 4 * q);
            }
        }

        short8 afh[4], afl[4], bfh[4], bfl[4];
#pragma unroll
        for (int i = 0; i < 4; ++i) {
            afh[i] = *(const short8*)&Ah[(wm + i * 16 + fr) * LDA + fk];
            afl[i] = *(const short8*)&Al[(wm + i * 16 + fr) * LDA + fk];
            bfh[i] = *(const short8*)&Bh[(wn + i * 16 + fr) * LDA + fk];
            bfl[i] = *(const short8*)&Bl[(wn + i * 16 + fr) * LDA + fk];
        }
#pragma unroll
        for (int i = 0; i < 4; ++i)
#pragma unroll
            for (int j = 0; j < 4; ++j) {
                acc[i][j] = __builtin_amdgcn_mfma_f32_16x16x32_bf16(afh[i], bfh[j], acc[i][j], 0, 0, 0);
                acc[i][j] = __builtin_amdgcn_mfma_f32_16x16x32_bf16(afh[i], bfl[j], acc[i][j], 0, 0, 0);
                acc[i][j] = __builtin_amdgcn_mfma_f32_16x16x32_bf16(afl[i], bfh[j], acc[i][j], 0, 0, 0);
            }
    }

    // epilogue: C/D layout col=lane&15, row=(lane>>4)*4+reg (guide m89/m91)
    float biasv[4];
#pragma unroll
    for (int j = 0; j < 4; ++j) {
        const int col = n0 + wn + j * 16 + fr;
        biasv[j] = b_ih[col] + b_hh[col];
    }
    const int rbase = (lane >> 4) * 4;
#pragma unroll
    for (int i = 0; i < 4; ++i)
#pragma unroll
        for (int j = 0; j < 4; ++j) {
            const int col = n0 + wn + j * 16 + fr;
#pragma unroll
            for (int r = 0; r < 4; ++r) {
                const int row = m0 + wm + i * 16 + rbase + r;
                xg[(size_t)row * G4 + col] = __float2half_rn(acc[i][j][r] + biasv[j]);
            }
        }
}

// ---------------------------------------------------------------------------
// Zero the padded per-WG progress flags (2 domains x 128 flags x 32 stride).
// ---------------------------------------------------------------------------
__global__ void zero_cnt(unsigned* flags) {
    flags[blockIdx.x * 1024 + threadIdx.x] = 0u;
}

// ---------------------------------------------------------------------------
// fast tanh: (1-e)/(1+e) with e=exp(-2|x|) via v_exp_f32. No overflow (e<=1),
// ~1e-7 abs error -- negligible vs the 2.4e-4/step fp16-xg noise. Removes the
// slow precise tanhf libcall from the serial combine->store critical path.
// ---------------------------------------------------------------------------
__device__ __forceinline__ float fast_tanh(float x) {
    const float e = __expf(-2.f * fabsf(x));
    const float r = __fdividef(1.f - e, 1.f + e);
    return copysignf(r, x);
}

// ---------------------------------------------------------------------------
// Phase B: persistent cooperative recurrence.
// Sync design (R3): per-WG progress flags, ONE PER 128-B CACHE LINE (no
// same-line writer serialization, no hot-line poll contention). NO per-step
// acquire fence: h is read with relaxed agent-scope atomic dword loads
// (coherence-point bypass), so nobody invalidates anybody's L1/L2 and xg/out
// lines stay cached. Producer: h stores are relaxed agent atomics
// (write-through), drained with a targeted s_waitcnt vmcnt(0) before the
// flag store. R4: s_sleep(2) backoff in the poll loop (cuts L3 poll-traffic
// congestion ~4x for <=~50ns/step detect latency) + fast_tanh in combine.
// ---------------------------------------------------------------------------
__global__ void __launch_bounds__(256, 1)
lstm_rec(const __half* __restrict__ xg, const float* __restrict__ Whh,
         float* __restrict__ out, unsigned* __restrict__ flags)
{
    extern __shared__ float sm[];
    float* Wsl = sm;                         // 24*768 = 18432 floats
    float* hsl = sm + 24 * H_SZ;             // 12288 floats (union with P)
    float* G   = sm + 24 * H_SZ + 12288;     // 384 floats

    const int tid = threadIdx.x;
    const int wg  = blockIdx.x;
    const int c   = wg & 1;        // batch group (sync domain)
    const int r   = wg >> 1;       // unit group 0..127
    const int u0  = r * 6;
    const int b0  = c * 16;

    // ---- load W_hh slice once: rows (gate*768 + u0 + j), gate<4, j<6 ----
    for (int i = tid; i < 24 * 192; i += 256) {
        const int rr = i / 192;              // local row 0..23
        const int kc = (i % 192) * 4;
        const int gate = rr / 6, j = rr % 6;
        const float4 v = *(const float4*)&Whh[(size_t)(gate * H_SZ + u0 + j) * H_SZ + kc];
        *(float4*)&Wsl[rr * H_SZ + kc] = v;
    }

    // dot-phase role
    const int ks     = tid & 31;             // K segment (k = 4*ks + 128*jj)
    const int tileId = tid >> 5;             // 0..7
    const int tr = (tileId & 1) * 12;        // row tile base
    const int tb = (tileId >> 1) * 4;        // batch tile base

    // combine-phase role (threads 0..95)
    const int cj = tid % 6;                  // unit within group
    const int cb = tid / 6;                  // batch within group
    float c_reg = 0.f;                       // cell state, register-resident

    unsigned* myflags = flags + c * 128 * FPAD;

    __builtin_amdgcn_fence(__ATOMIC_ACQUIRE, "agent");  // once: clear poison
    __syncthreads();

    for (int t = 0; t < T_LEN; ++t) {
        // ---- prefetch xg[t] for the combine (independent of h) ----
        float xpi = 0.f, xpf = 0.f, xpg = 0.f, xpo = 0.f;
        if (tid < 96) {
            const size_t xbase = ((size_t)t * B_SZ + (b0 + cb)) * G4 + u0 + cj;
            xpi = __half2float(xg[xbase + 0 * H_SZ]);
            xpf = __half2float(xg[xbase + 1 * H_SZ]);
            xpg = __half2float(xg[xbase + 2 * H_SZ]);
            xpo = __half2float(xg[xbase + 3 * H_SZ]);
        }

        if (t == 0) {
            for (int i = tid; i < 384; i += 256) G[i] = 0.f;  // h_prev = 0
            __syncthreads();
        } else {
            // ---- wait: all 128 WGs of this domain finished step t-1 ----
            if (tid < 128) {
                while (__hip_atomic_load(&myflags[tid * FPAD], __ATOMIC_RELAXED,
                                         __HIP_MEMORY_SCOPE_AGENT) < (unsigned)t) {
                    __builtin_amdgcn_s_sleep(2);   // backoff: cut L3 poll traffic
                }
            }
            __syncthreads();

            // ---- stage h_prev[b0..b0+16][:] into LDS via coherent dword
            //      loads (no fence needed). b = i/3, k = tid + (i%3)*256. ----
            float hreg[48];
#pragma unroll
            for (int i = 0; i < 48; ++i) {
                const int b = i / 3;
                const int k = tid + (i % 3) * 256;
                hreg[i] = __hip_atomic_load(
                    &out[((size_t)(b0 + b) * T_LEN + (t - 1)) * H_SZ + k],
                    __ATOMIC_RELAXED, __HIP_MEMORY_SCOPE_AGENT);
            }
#pragma unroll
            for (int i = 0; i < 48; ++i) {
                const int b = i / 3;
                const int k = tid + (i % 3) * 256;
                hsl[b * H_SZ + k] = hreg[i];
            }
            __syncthreads();

            // ---- dot: acc[12 rows][4 batches] over 24-element K segment ----
            float acc[12][4];
#pragma unroll
            for (int a = 0; a < 12; ++a)
#pragma unroll
                for (int q = 0; q < 4; ++q) acc[a][q] = 0.f;

            for (int jj = 0; jj < 6; ++jj) {
                const int k = ks * 4 + jj * 128;   // lanes stride-1 in k
                float4 hv[4];
#pragma unroll
                for (int q = 0; q < 4; ++q)
                    hv[q] = *(const float4*)&hsl[(tb + q) * H_SZ + k];
#pragma unroll
                for (int a = 0; a < 12; ++a) {
                    const float4 wv = *(const float4*)&Wsl[(tr + a) * H_SZ + k];
#pragma unroll
                    for (int q = 0; q < 4; ++q) {
                        acc[a][q] = fmaf(wv.x, hv[q].x, acc[a][q]);
                        acc[a][q] = fmaf(wv.y, hv[q].y, acc[a][q]);
                        acc[a][q] = fmaf(wv.z, hv[q].z, acc[a][q]);
                        acc[a][q] = fmaf(wv.w, hv[q].w, acc[a][q]);
                    }
                }
            }
            __syncthreads();                 // hsl reads done -> reuse as P

            // ---- write partials P[out 0..383][ks 0..31] ----
            float* P = hsl;
#pragma unroll
            for (int a = 0; a < 12; ++a)
#pragma unroll
                for (int q = 0; q < 4; ++q)
                    P[((tr + a) * 16 + (tb + q)) * 32 + ks] = acc[a][q];
            __syncthreads();

            // ---- reduce (diagonal reads: bank-conflict-free) ----
            for (int oi = tid; oi < 384; oi += 256) {
                float s = 0.f;
#pragma unroll
                for (int kk = 0; kk < 32; ++kk) {
                    const int k2 = (kk + oi) & 31;
                    s += P[oi * 32 + k2];
                }
                G[oi] = s;
            }
            __syncthreads();
        }

        // ---- gate combine: threads 0..95, one (unit, batch) each ----
        if (tid < 96) {
            const float pi = G[(0 * 6 + cj) * 16 + cb] + xpi;
            const float pf = G[(1 * 6 + cj) * 16 + cb] + xpf;
            const float pg = G[(2 * 6 + cj) * 16 + cb] + xpg;
            const float po = G[(3 * 6 + cj) * 16 + cb] + xpo;
            const float ig = 1.f / (1.f + __expf(-pi));
            const float fg = 1.f / (1.f + __expf(-pf));
            const float gg = fast_tanh(pg);
            const float og = 1.f / (1.f + __expf(-po));
            c_reg = fg * c_reg + ig * gg;
            const float h = og * fast_tanh(c_reg);
            // write-through to the device coherence point; readers bypass too
            __hip_atomic_store(&out[((size_t)(b0 + cb) * T_LEN + t) * H_SZ + u0 + cj],
                               h, __ATOMIC_RELAXED, __HIP_MEMORY_SCOPE_AGENT);
        }
        // drain only vmem stores, then barrier so ALL waves' stores are done
        asm volatile("s_waitcnt vmcnt(0)" ::: "memory");
        __syncthreads();

        // ---- publish: one relaxed flag store (flag = steps completed) ----
        if (tid == 0) {
            __hip_atomic_store(&myflags[r * FPAD], (unsigned)(t + 1),
                               __ATOMIC_RELAXED, __HIP_MEMORY_SCOPE_AGENT);
        }
    }
}

// ---------------------------------------------------------------------------
extern "C" void kernel_launch(void* const* d_in, const int* in_sizes, int n_in,
                              void* d_out, int out_size, void* d_ws, size_t ws_size,
                              hipStream_t stream)
{
    (void)in_sizes; (void)n_in; (void)out_size; (void)ws_size;
    const float* hidden = (const float*)d_in[0];
    const float* W_ih   = (const float*)d_in[1];
    const float* W_hh   = (const float*)d_in[2];
    const float* b_ih   = (const float*)d_in[3];
    const float* b_hh   = (const float*)d_in[4];
    float* out = (float*)d_out;

    __half* xg = (__half*)d_ws;                                  // 201,326,592 B
    unsigned* flags = (unsigned*)((char*)d_ws +
                      (size_t)T_LEN * B_SZ * G4 * sizeof(__half)); // 8192 u32

    zero_cnt<<<dim3(8), dim3(1024), 0, stream>>>(flags);
    xg_gemm<<<dim3(G4 / 128, (B_SZ * T_LEN) / 128), dim3(256), 0, stream>>>(
        hidden, W_ih, b_ih, b_hh, xg);

    const int smem = (24 * H_SZ + 12288 + 384) * (int)sizeof(float);  // 124,416 B
    hipFuncSetAttribute((const void*)lstm_rec,
                        hipFuncAttributeMaxDynamicSharedMemorySize, smem);
    void* args[] = { (void*)&xg, (void*)&W_hh, (void*)&out, (void*)&flags };
    hipLaunchCooperativeKernel((void*)lstm_rec, dim3(256), dim3(256),
                               args, (unsigned)smem, stream);
}